// Round 14
// baseline (552.231 us; speedup 1.0000x reference)
//
#include <hip/hip_runtime.h>
#include <hip/hip_fp16.h>

#define HID 64
#define FSH 9                  // nodes per fill bucket = 512
#define FB 196                 // buckets: 196*512 = 100352 >= N
#define FCAP 160               // per-(block,bucket) staging cap (mean 83.6, +8.3 sigma)
#define FCH 16384              // edges per phase-A block (196 blocks, block-private slices)
// packed record: loc(9b) << 17 | src(17b); requires N <= 131072

// ---------------- fill phase A: block-private binning, LDS cursors, no global atomics ----------------
__global__ __launch_bounds__(256) void fillA_kernel(const int* __restrict__ src,
                                                    const int* __restrict__ dst,
                                                    unsigned int* __restrict__ recA,
                                                    int* __restrict__ cnt, int E) {
    __shared__ int cur[FB];
    int t = threadIdx.x;
    for (int i = t; i < FB; i += 256) cur[i] = 0;
    __syncthreads();
    int base = blockIdx.x * FCH;
    int lim = E - base;
    if (lim > FCH) lim = FCH;
    unsigned int* myrec = recA + (size_t)blockIdx.x * FB * FCAP;
    for (int i = t; i < lim; i += 256) {
        int d = dst[base + i];
        int s = src[base + i];
        int bkt = d >> FSH;
        int idx = atomicAdd(&cur[bkt], 1);   // LDS atomic
        if (idx < FCAP)
            myrec[(size_t)bkt * FCAP + idx] =
                ((unsigned int)(d & ((1 << FSH) - 1)) << 17) | (unsigned int)s;
    }
    __syncthreads();
    for (int i = t; i < FB; i += 256) {
        int c = cur[i];
        cnt[blockIdx.x * FB + i] = (c < FCAP) ? c : FCAP;
    }
}

// ---------------- per-bucket totals (sum over blocks) + exclusive scan -> bbase ----------------
__global__ __launch_bounds__(256) void sumscan_kernel(const int* __restrict__ cnt,
                                                      int* __restrict__ bbase, int nblk) {
    __shared__ int buf[256];
    int t = threadIdx.x;
    int total = 0;
    if (t < FB)
        for (int blk = 0; blk < nblk; ++blk) total += cnt[blk * FB + t];
    buf[t] = total;
    __syncthreads();
#pragma unroll
    for (int o = 1; o < 256; o <<= 1) {
        int v = (t >= o) ? buf[t - o] : 0;
        __syncthreads();
        buf[t] += v;
        __syncthreads();
    }
    if (t < FB) bbase[t] = buf[t] - total;  // exclusive
}

// ---------------- fill phase B: per-bucket hist + scan + rowptr/dinv + fine fill ----------------
__global__ __launch_bounds__(256) void fillB_kernel(const int* __restrict__ cnt,
                                                    const int* __restrict__ bbase,
                                                    const unsigned int* __restrict__ recA,
                                                    int* __restrict__ rowptr,
                                                    float* __restrict__ dinv,
                                                    int* __restrict__ col, int N, int nblk) {
    __shared__ int hist[1 << FSH];   // local degree -> later cursor
    __shared__ int buf[256];
    int b = blockIdx.x;
    int t = threadIdx.x;
    int n0 = b << FSH;
    for (int i = t; i < (1 << FSH); i += 256) hist[i] = 0;
    __syncthreads();
    for (int blk = 0; blk < nblk; ++blk) {
        int c = cnt[blk * FB + b];
        const unsigned int* rA = recA + ((size_t)blk * FB + b) * FCAP;
        for (int r = t; r < c; r += 256) atomicAdd(&hist[rA[r] >> 17], 1);
    }
    __syncthreads();
    // scan 512 local degrees (2 per thread)
    int a0 = hist[2 * t], a1 = hist[2 * t + 1];
    int pair = a0 + a1;
    buf[t] = pair;
    __syncthreads();
#pragma unroll
    for (int o = 1; o < 256; o <<= 1) {
        int tv = (t >= o) ? buf[t - o] : 0;
        __syncthreads();
        buf[t] += tv;
        __syncthreads();
    }
    int excl = buf[t] - pair + bbase[b];  // exclusive over pairs + bucket base
    int n_a = n0 + 2 * t, n_b = n0 + 2 * t + 1;
    if (n_a <= N) rowptr[n_a] = excl;
    if (n_b <= N) rowptr[n_b] = excl + a0;
    if (n_a < N) dinv[n_a] = 1.0f / sqrtf((float)(a0 + 1));
    if (n_b < N) dinv[n_b] = 1.0f / sqrtf((float)(a1 + 1));
    __syncthreads();
    hist[2 * t] = excl;            // reuse hist as cursors
    hist[2 * t + 1] = excl + a0;
    __syncthreads();
    for (int blk = 0; blk < nblk; ++blk) {
        int c = cnt[blk * FB + b];
        const unsigned int* rA = recA + ((size_t)blk * FB + b) * FCAP;
        for (int r = t; r < c; r += 256) {
            unsigned int rec = rA[r];
            int pos = atomicAdd(&hist[rec >> 17], 1);
            col[pos] = (int)(rec & 0x1ffffu);
        }
    }
}

// ---------------- dense linear + dinv scale -> f16 rows: out[n,:] = f16(dinv[n]*(x[n,:]@W)) ----------------
template <int K, typename XT>
__global__ __launch_bounds__(256) void linscale_kernel(const XT* __restrict__ x,
                                                       const float* __restrict__ W,
                                                       const float* __restrict__ dinv,
                                                       __half* __restrict__ out, int N) {
    __shared__ float4 Wl[K * 16];
    const float4* W4 = reinterpret_cast<const float4*>(W);
    for (int i = threadIdx.x; i < K * 16; i += blockDim.x) Wl[i] = W4[i];
    __syncthreads();
    int node = blockIdx.x * blockDim.x + threadIdx.x;
    if (node >= N) return;
    float4 acc[16];
#pragma unroll
    for (int c = 0; c < 16; ++c) acc[c] = make_float4(0.f, 0.f, 0.f, 0.f);
    const XT* xr = x + (size_t)node * K;
    for (int k = 0; k < K; ++k) {
        float xv = (float)xr[k];
#pragma unroll
        for (int c = 0; c < 16; ++c) {
            float4 w = Wl[k * 16 + c];
            acc[c].x += xv * w.x;
            acc[c].y += xv * w.y;
            acc[c].z += xv * w.z;
            acc[c].w += xv * w.w;
        }
    }
    float dv = dinv[node];
    __half2* o = reinterpret_cast<__half2*>(out + (size_t)node * HID);
#pragma unroll
    for (int c = 0; c < 16; ++c) {
        o[c * 2 + 0] = __floats2half2_rn(acc[c].x * dv, acc[c].y * dv);
        o[c * 2 + 1] = __floats2half2_rn(acc[c].z * dv, acc[c].w * dv);
    }
}

// ---------------- gather-aggregate: half2 lanes, 2 rows per wave ----------------
// out[d,:] = f16( relu(dinv[d]*(hs[d,:] + sum_e hs[col[e],:]) + b) )
__global__ __launch_bounds__(256) void gather_kernel(const int* __restrict__ rowptr,
                                                     const int* __restrict__ col,
                                                     const float* __restrict__ dinv,
                                                     const __half2* __restrict__ hs2,
                                                     const float* __restrict__ b,
                                                     __half2* __restrict__ out2, int N) {
    int lane = threadIdx.x & 63;
    int hf = lane >> 5;       // which row of the pair
    int gl = lane & 31;       // lane within 32-group = half2 channel pair
    int wid = (blockIdx.x * blockDim.x + threadIdx.x) >> 6;
    int nw = (gridDim.x * blockDim.x) >> 6;
    float bx = b[2 * gl], by = b[2 * gl + 1];
    for (int dbase = wid * 2; dbase < N; dbase += nw * 2) {
        int d = dbase + hf;
        bool act = d < N;
        int dd = act ? d : N - 1;
        int beg = rowptr[dd];
        int end = act ? rowptr[dd + 1] : beg;
        float2 acc = __half22float2(hs2[((size_t)dd << 5) + gl]);  // self-loop
        for (int ebase = beg; ebase < end; ebase += 32) {
            int e = ebase + gl;
            int cv = (e < end) ? col[e] : 0;   // group-strided load: <=32 edges
            int cnt = end - ebase;
            if (cnt > 32) cnt = 32;
            int k = 0;
            for (; k + 4 <= cnt; k += 4) {
                int s0 = __shfl(cv, k + 0, 32);
                int s1 = __shfl(cv, k + 1, 32);
                int s2 = __shfl(cv, k + 2, 32);
                int s3 = __shfl(cv, k + 3, 32);
                float2 v0 = __half22float2(hs2[((size_t)s0 << 5) + gl]);
                float2 v1 = __half22float2(hs2[((size_t)s1 << 5) + gl]);
                float2 v2 = __half22float2(hs2[((size_t)s2 << 5) + gl]);
                float2 v3 = __half22float2(hs2[((size_t)s3 << 5) + gl]);
                acc.x += (v0.x + v1.x) + (v2.x + v3.x);
                acc.y += (v0.y + v1.y) + (v2.y + v3.y);
            }
            for (; k < cnt; ++k) {
                int s = __shfl(cv, k, 32);
                float2 v = __half22float2(hs2[((size_t)s << 5) + gl]);
                acc.x += v.x; acc.y += v.y;
            }
        }
        if (act) {
            float dv = dinv[d];
            float rx = fmaxf(fmaf(acc.x, dv, bx), 0.f);
            float ry = fmaxf(fmaf(acc.y, dv, by), 0.f);
            out2[((size_t)d << 5) + gl] = __floats2half2_rn(rx, ry);
        }
    }
}

// ---------------- MLP head, thread-per-node: out[i] = relu(h@Wh1+bh1) @ Wh2 + bh2 ----------------
__global__ __launch_bounds__(256) void head_kernel(const __half* __restrict__ h,
                                                   const float* __restrict__ Wh1,
                                                   const float* __restrict__ bh1,
                                                   const float* __restrict__ Wh2,
                                                   const float* __restrict__ bh2,
                                                   float* __restrict__ out, int N) {
    __shared__ float4 Wl[64 * 16];
    __shared__ float bhs[64];
    __shared__ float w2s[64];
    const float4* W4 = reinterpret_cast<const float4*>(Wh1);
    for (int i = threadIdx.x; i < 64 * 16; i += blockDim.x) Wl[i] = W4[i];
    if (threadIdx.x < 64) {
        bhs[threadIdx.x] = bh1[threadIdx.x];
        w2s[threadIdx.x] = Wh2[threadIdx.x];
    }
    __syncthreads();
    int node = blockIdx.x * blockDim.x + threadIdx.x;
    if (node >= N) return;
    float4 acc[16];
#pragma unroll
    for (int c = 0; c < 16; ++c) acc[c] = make_float4(0.f, 0.f, 0.f, 0.f);
    const __half* hr = h + ((size_t)node << 6);
    for (int k = 0; k < 64; ++k) {
        float xv = __half2float(hr[k]);
#pragma unroll
        for (int c = 0; c < 16; ++c) {
            float4 w = Wl[k * 16 + c];
            acc[c].x += xv * w.x;
            acc[c].y += xv * w.y;
            acc[c].z += xv * w.z;
            acc[c].w += xv * w.w;
        }
    }
    float o = 0.f;
#pragma unroll
    for (int c = 0; c < 16; ++c) {
        o += fmaxf(acc[c].x + bhs[4 * c + 0], 0.f) * w2s[4 * c + 0];
        o += fmaxf(acc[c].y + bhs[4 * c + 1], 0.f) * w2s[4 * c + 1];
        o += fmaxf(acc[c].z + bhs[4 * c + 2], 0.f) * w2s[4 * c + 2];
        o += fmaxf(acc[c].w + bhs[4 * c + 3], 0.f) * w2s[4 * c + 3];
    }
    out[node] = o + bh2[0];
}

extern "C" void kernel_launch(void* const* d_in, const int* in_sizes, int n_in,
                              void* d_out, int out_size, void* d_ws, size_t ws_size,
                              hipStream_t stream) {
    const float* x = (const float*)d_in[0];
    const int* edge = (const int*)d_in[1];   // harness passes integer inputs as int32
    const float* W1 = (const float*)d_in[2];
    const float* b1 = (const float*)d_in[3];
    const float* W2 = (const float*)d_in[4];
    const float* b2 = (const float*)d_in[5];
    const float* W3 = (const float*)d_in[6];
    const float* b3 = (const float*)d_in[7];
    const float* Wh1 = (const float*)d_in[8];
    const float* bh1 = (const float*)d_in[9];
    const float* Wh2 = (const float*)d_in[10];
    const float* bh2 = (const float*)d_in[11];

    int N = in_sizes[0] / 61;   // 100000
    int E = in_sizes[1] / 2;    // 3200000
    const int* srcs = edge;
    const int* dsts = edge + E;
    float* out = (float*)d_out;

    // workspace: dinv(N) | rowptr(N+1) | cnt(gA*FB) | bbase(FB) | col(E) | Ah(N*64 f16) | Bh(N*64 f16)
    // fill staging recA (gA*FB*FCAP*4 = 24.6MB) aliases Ah+Bh (25.6MB contiguous, dead until linscale1)
    char* ws = (char*)d_ws;
    size_t off = 0;
    auto alloc = [&](size_t bytes) {
        void* p = ws + off;
        off += (bytes + 255) & ~(size_t)255;
        return p;
    };
    int gA = (E + FCH - 1) / FCH;   // 196
    float* dinv = (float*)alloc((size_t)N * 4);
    int* rowptr = (int*)alloc((size_t)(N + 1) * 4);
    int* cnt = (int*)alloc((size_t)gA * FB * 4);
    int* bbase = (int*)alloc((size_t)FB * 4);
    int* col = (int*)alloc((size_t)E * 4);
    __half* Ah = (__half*)alloc((size_t)N * HID * 2);
    __half* Bh = (__half*)alloc((size_t)N * HID * 2);
    if (off > ws_size) return;  // fail cleanly (absmax), not a fault
    unsigned int* recA = (unsigned int*)Ah;  // alias: staging dead after fillB
    if ((size_t)gA * FB * FCAP * 4 > (size_t)N * HID * 4) return;  // staging must fit Ah+Bh

    int gN = (N + 255) / 256;

    // ---- CSR build (once, reused by all 3 layers) ----
    fillA_kernel<<<gA, 256, 0, stream>>>(srcs, dsts, recA, cnt, E);
    sumscan_kernel<<<1, 256, 0, stream>>>(cnt, bbase, gA);
    fillB_kernel<<<FB, 256, 0, stream>>>(cnt, bbase, recA, rowptr, dinv, col, N, gA);

    // ---- layer 1 (K=61) ----
    linscale_kernel<61, float><<<gN, 256, 0, stream>>>(x, W1, dinv, Bh, N);
    gather_kernel<<<4096, 256, 0, stream>>>(rowptr, col, dinv,
                                            (const __half2*)Bh, b1, (__half2*)Ah, N);

    // ---- layer 2 (K=64) ----
    linscale_kernel<64, __half><<<gN, 256, 0, stream>>>(Ah, W2, dinv, Bh, N);
    gather_kernel<<<4096, 256, 0, stream>>>(rowptr, col, dinv,
                                            (const __half2*)Bh, b2, (__half2*)Ah, N);

    // ---- layer 3 (K=64) ----
    linscale_kernel<64, __half><<<gN, 256, 0, stream>>>(Ah, W3, dinv, Bh, N);
    gather_kernel<<<4096, 256, 0, stream>>>(rowptr, col, dinv,
                                            (const __half2*)Bh, b3, (__half2*)Ah, N);

    // ---- MLP head ----
    head_kernel<<<gN, 256, 0, stream>>>(Ah, Wh1, bh1, Wh2, bh2, out, N);
}

// Round 15
// 433.895 us; speedup vs baseline: 1.2727x; 1.2727x over previous
//
#include <hip/hip_runtime.h>
#include <hip/hip_fp16.h>

#define HID 64
#define FSH 8                  // nodes per bucket = 256
#define FB 392                 // buckets: 392*256 = 100352 >= N
#define SCAP 9216              // per-bucket global staging capacity (mean 8163, +11 sigma)
#define FCH 14336              // edges per fillA block (LDS counting-sort chunk)
// packed record: loc(8b) << 17 | src(17b); requires N <= 131072

// ---------------- zero int buffer ----------------
__global__ void zero_kernel(int* __restrict__ p, int n) {
    int i = blockIdx.x * blockDim.x + threadIdx.x;
    if (i < n) p[i] = 0;
}

// ---------------- fill phase A: per-block LDS counting sort + coalesced bucket appends ----------------
__global__ __launch_bounds__(256) void fillA_kernel(const int* __restrict__ src,
                                                    const int* __restrict__ dst,
                                                    int* __restrict__ gcur,
                                                    unsigned int* __restrict__ recA,
                                                    int E) {
    __shared__ unsigned int srec[FCH];          // 56 KB
    __shared__ int hist[FB], lbase[FB], lcur[FB], gpos[FB];
    __shared__ int buf[256];
    int t = threadIdx.x;
    int base = blockIdx.x * FCH;
    int lim = E - base;
    if (lim > FCH) lim = FCH;
    if (lim <= 0) return;
    for (int i = t; i < FB; i += 256) hist[i] = 0;
    __syncthreads();
    for (int i = t; i < lim; i += 256) atomicAdd(&hist[dst[base + i] >> FSH], 1);
    __syncthreads();
    // pair-scan hist[0..FB) -> lbase (exclusive)
    int i0 = 2 * t, i1 = 2 * t + 1;
    int a0 = (i0 < FB) ? hist[i0] : 0;
    int a1 = (i1 < FB) ? hist[i1] : 0;
    int pair = a0 + a1;
    buf[t] = pair;
    __syncthreads();
#pragma unroll
    for (int o = 1; o < 256; o <<= 1) {
        int v = (t >= o) ? buf[t - o] : 0;
        __syncthreads();
        buf[t] += v;
        __syncthreads();
    }
    int excl = buf[t] - pair;
    if (i0 < FB) { lbase[i0] = excl;      lcur[i0] = excl; }
    if (i1 < FB) { lbase[i1] = excl + a0; lcur[i1] = excl + a0; }
    __syncthreads();
    // reserve global space (one atomic per bucket per block)
    for (int i = t; i < FB; i += 256) gpos[i] = atomicAdd(&gcur[i], hist[i]);
    __syncthreads();
    // counting-sort records into LDS
    for (int i = t; i < lim; i += 256) {
        int d = dst[base + i];
        int s = src[base + i];
        int bkt = d >> FSH;
        int idx = atomicAdd(&lcur[bkt], 1);
        srec[idx] = ((unsigned int)(d & ((1 << FSH) - 1)) << 17) | (unsigned int)s;
    }
    __syncthreads();
    // coalesced copy of each bucket's run to its global staging region
    int w = t >> 6, lane = t & 63;
    for (int bkt = w; bkt < FB; bkt += 4) {
        int L = hist[bkt], lb = lbase[bkt], gp = gpos[bkt];
        for (int j = lane; j < L; j += 64) {
            int g = gp + j;
            if (g < SCAP) recA[(size_t)bkt * SCAP + g] = srec[lb + j];
        }
    }
}

// ---------------- exclusive scan of FB bucket totals -> bbase ----------------
__global__ __launch_bounds__(256) void bucketscan_kernel(const int* __restrict__ gcur,
                                                         int* __restrict__ bbase) {
    __shared__ int buf[256];
    int t = threadIdx.x;
    int i0 = 2 * t, i1 = 2 * t + 1;
    int a0 = (i0 < FB) ? min(gcur[i0], SCAP) : 0;
    int a1 = (i1 < FB) ? min(gcur[i1], SCAP) : 0;
    int pair = a0 + a1;
    buf[t] = pair;
    __syncthreads();
#pragma unroll
    for (int o = 1; o < 256; o <<= 1) {
        int v = (t >= o) ? buf[t - o] : 0;
        __syncthreads();
        buf[t] += v;
        __syncthreads();
    }
    int excl = buf[t] - pair;
    if (i0 < FB) bbase[i0] = excl;
    if (i1 < FB) bbase[i1] = excl + a0;
}

// ---------------- fill phase B: per-bucket LDS CSR build + coalesced col writeback ----------------
__global__ __launch_bounds__(256) void fillB_kernel(const int* __restrict__ gcur,
                                                    const int* __restrict__ bbase,
                                                    const unsigned int* __restrict__ recA,
                                                    int* __restrict__ rowptr,
                                                    float* __restrict__ dinv,
                                                    int* __restrict__ col, int N) {
    __shared__ unsigned int lcol[SCAP];         // 36 KB
    __shared__ int hist[256], cur[256], buf[256];
    int b = blockIdx.x, t = threadIdx.x;
    int n0 = b << FSH;
    hist[t] = 0;
    __syncthreads();
    int cnt = gcur[b];
    if (cnt > SCAP) cnt = SCAP;
    const unsigned int* rA = recA + (size_t)b * SCAP;
    for (int r = t; r < cnt; r += 256) atomicAdd(&hist[rA[r] >> 17], 1);
    __syncthreads();
    int a = hist[t];
    buf[t] = a;
    __syncthreads();
#pragma unroll
    for (int o = 1; o < 256; o <<= 1) {
        int v = (t >= o) ? buf[t - o] : 0;
        __syncthreads();
        buf[t] += v;
        __syncthreads();
    }
    int excl = buf[t] - a;           // local exclusive
    int node = n0 + t;
    int rbase = bbase[b];
    if (node <= N) rowptr[node] = rbase + excl;   // includes rowptr[N] at node==N
    if (node < N) dinv[node] = 1.0f / sqrtf((float)(a + 1));
    cur[t] = excl;
    __syncthreads();
    for (int r = t; r < cnt; r += 256) {
        unsigned int rec = rA[r];
        int pos = atomicAdd(&cur[rec >> 17], 1);  // LDS cursor, local position
        lcol[pos] = rec & 0x1ffffu;
    }
    __syncthreads();
    for (int j = t; j < cnt; j += 256) col[rbase + j] = (int)lcol[j];  // coalesced
}

// ---------------- dense linear + dinv scale -> f16 rows: out[n,:] = f16(dinv[n]*(x[n,:]@W)) ----------------
template <int K, typename XT>
__global__ __launch_bounds__(256) void linscale_kernel(const XT* __restrict__ x,
                                                       const float* __restrict__ W,
                                                       const float* __restrict__ dinv,
                                                       __half* __restrict__ out, int N) {
    __shared__ float4 Wl[K * 16];
    const float4* W4 = reinterpret_cast<const float4*>(W);
    for (int i = threadIdx.x; i < K * 16; i += blockDim.x) Wl[i] = W4[i];
    __syncthreads();
    int node = blockIdx.x * blockDim.x + threadIdx.x;
    if (node >= N) return;
    float4 acc[16];
#pragma unroll
    for (int c = 0; c < 16; ++c) acc[c] = make_float4(0.f, 0.f, 0.f, 0.f);
    const XT* xr = x + (size_t)node * K;
    for (int k = 0; k < K; ++k) {
        float xv = (float)xr[k];
#pragma unroll
        for (int c = 0; c < 16; ++c) {
            float4 w = Wl[k * 16 + c];
            acc[c].x += xv * w.x;
            acc[c].y += xv * w.y;
            acc[c].z += xv * w.z;
            acc[c].w += xv * w.w;
        }
    }
    float dv = dinv[node];
    __half2* o = reinterpret_cast<__half2*>(out + (size_t)node * HID);
#pragma unroll
    for (int c = 0; c < 16; ++c) {
        o[c * 2 + 0] = __floats2half2_rn(acc[c].x * dv, acc[c].y * dv);
        o[c * 2 + 1] = __floats2half2_rn(acc[c].z * dv, acc[c].w * dv);
    }
}

// ---------------- gather-aggregate: half2 lanes, 2 rows per wave ----------------
// out[d,:] = f16( relu(dinv[d]*(hs[d,:] + sum_e hs[col[e],:]) + b) )
__global__ __launch_bounds__(256) void gather_kernel(const int* __restrict__ rowptr,
                                                     const int* __restrict__ col,
                                                     const float* __restrict__ dinv,
                                                     const __half2* __restrict__ hs2,
                                                     const float* __restrict__ b,
                                                     __half2* __restrict__ out2, int N) {
    int lane = threadIdx.x & 63;
    int hf = lane >> 5;       // which row of the pair
    int gl = lane & 31;       // lane within 32-group = half2 channel pair
    int wid = (blockIdx.x * blockDim.x + threadIdx.x) >> 6;
    int nw = (gridDim.x * blockDim.x) >> 6;
    float bx = b[2 * gl], by = b[2 * gl + 1];
    for (int dbase = wid * 2; dbase < N; dbase += nw * 2) {
        int d = dbase + hf;
        bool act = d < N;
        int dd = act ? d : N - 1;
        int beg = rowptr[dd];
        int end = act ? rowptr[dd + 1] : beg;
        float2 acc = __half22float2(hs2[((size_t)dd << 5) + gl]);  // self-loop
        for (int ebase = beg; ebase < end; ebase += 32) {
            int e = ebase + gl;
            int cv = (e < end) ? col[e] : 0;   // group-strided load: <=32 edges
            int cnt = end - ebase;
            if (cnt > 32) cnt = 32;
            int k = 0;
            for (; k + 4 <= cnt; k += 4) {
                int s0 = __shfl(cv, k + 0, 32);
                int s1 = __shfl(cv, k + 1, 32);
                int s2 = __shfl(cv, k + 2, 32);
                int s3 = __shfl(cv, k + 3, 32);
                float2 v0 = __half22float2(hs2[((size_t)s0 << 5) + gl]);
                float2 v1 = __half22float2(hs2[((size_t)s1 << 5) + gl]);
                float2 v2 = __half22float2(hs2[((size_t)s2 << 5) + gl]);
                float2 v3 = __half22float2(hs2[((size_t)s3 << 5) + gl]);
                acc.x += (v0.x + v1.x) + (v2.x + v3.x);
                acc.y += (v0.y + v1.y) + (v2.y + v3.y);
            }
            for (; k < cnt; ++k) {
                int s = __shfl(cv, k, 32);
                float2 v = __half22float2(hs2[((size_t)s << 5) + gl]);
                acc.x += v.x; acc.y += v.y;
            }
        }
        if (act) {
            float dv = dinv[d];
            float rx = fmaxf(fmaf(acc.x, dv, bx), 0.f);
            float ry = fmaxf(fmaf(acc.y, dv, by), 0.f);
            out2[((size_t)d << 5) + gl] = __floats2half2_rn(rx, ry);
        }
    }
}

// ---------------- MLP head, thread-per-node: out[i] = relu(h@Wh1+bh1) @ Wh2 + bh2 ----------------
__global__ __launch_bounds__(256) void head_kernel(const __half* __restrict__ h,
                                                   const float* __restrict__ Wh1,
                                                   const float* __restrict__ bh1,
                                                   const float* __restrict__ Wh2,
                                                   const float* __restrict__ bh2,
                                                   float* __restrict__ out, int N) {
    __shared__ float4 Wl[64 * 16];
    __shared__ float bhs[64];
    __shared__ float w2s[64];
    const float4* W4 = reinterpret_cast<const float4*>(Wh1);
    for (int i = threadIdx.x; i < 64 * 16; i += blockDim.x) Wl[i] = W4[i];
    if (threadIdx.x < 64) {
        bhs[threadIdx.x] = bh1[threadIdx.x];
        w2s[threadIdx.x] = Wh2[threadIdx.x];
    }
    __syncthreads();
    int node = blockIdx.x * blockDim.x + threadIdx.x;
    if (node >= N) return;
    float4 acc[16];
#pragma unroll
    for (int c = 0; c < 16; ++c) acc[c] = make_float4(0.f, 0.f, 0.f, 0.f);
    const __half* hr = h + ((size_t)node << 6);
    for (int k = 0; k < 64; ++k) {
        float xv = __half2float(hr[k]);
#pragma unroll
        for (int c = 0; c < 16; ++c) {
            float4 w = Wl[k * 16 + c];
            acc[c].x += xv * w.x;
            acc[c].y += xv * w.y;
            acc[c].z += xv * w.z;
            acc[c].w += xv * w.w;
        }
    }
    float o = 0.f;
#pragma unroll
    for (int c = 0; c < 16; ++c) {
        o += fmaxf(acc[c].x + bhs[4 * c + 0], 0.f) * w2s[4 * c + 0];
        o += fmaxf(acc[c].y + bhs[4 * c + 1], 0.f) * w2s[4 * c + 1];
        o += fmaxf(acc[c].z + bhs[4 * c + 2], 0.f) * w2s[4 * c + 2];
        o += fmaxf(acc[c].w + bhs[4 * c + 3], 0.f) * w2s[4 * c + 3];
    }
    out[node] = o + bh2[0];
}

extern "C" void kernel_launch(void* const* d_in, const int* in_sizes, int n_in,
                              void* d_out, int out_size, void* d_ws, size_t ws_size,
                              hipStream_t stream) {
    const float* x = (const float*)d_in[0];
    const int* edge = (const int*)d_in[1];   // harness passes integer inputs as int32
    const float* W1 = (const float*)d_in[2];
    const float* b1 = (const float*)d_in[3];
    const float* W2 = (const float*)d_in[4];
    const float* b2 = (const float*)d_in[5];
    const float* W3 = (const float*)d_in[6];
    const float* b3 = (const float*)d_in[7];
    const float* Wh1 = (const float*)d_in[8];
    const float* bh1 = (const float*)d_in[9];
    const float* Wh2 = (const float*)d_in[10];
    const float* bh2 = (const float*)d_in[11];

    int N = in_sizes[0] / 61;   // 100000
    int E = in_sizes[1] / 2;    // 3200000
    const int* srcs = edge;
    const int* dsts = edge + E;
    float* out = (float*)d_out;

    // workspace: dinv(N) | rowptr(N+1) | gcur(FB) | bbase(FB) | col(E) | Ah(N*64 f16) | Bh(N*64 f16)
    // fill staging recA (FB*SCAP*4 = 14.45MB) aliases Ah+Bh (25.6MB contiguous, dead until linscale1)
    char* ws = (char*)d_ws;
    size_t off = 0;
    auto alloc = [&](size_t bytes) {
        void* p = ws + off;
        off += (bytes + 255) & ~(size_t)255;
        return p;
    };
    float* dinv = (float*)alloc((size_t)N * 4);
    int* rowptr = (int*)alloc((size_t)(N + 1) * 4);
    int* gcur = (int*)alloc((size_t)FB * 4);
    int* bbase = (int*)alloc((size_t)FB * 4);
    int* col = (int*)alloc((size_t)E * 4);
    __half* Ah = (__half*)alloc((size_t)N * HID * 2);
    __half* Bh = (__half*)alloc((size_t)N * HID * 2);
    if (off > ws_size) return;  // fail cleanly (absmax), not a fault
    unsigned int* recA = (unsigned int*)Ah;  // alias: staging dead after fillB

    int gN = (N + 255) / 256;
    int gA = (E + FCH - 1) / FCH;   // 224

    // ---- CSR build (once, reused by all 3 layers) ----
    zero_kernel<<<(FB + 255) / 256, 256, 0, stream>>>(gcur, FB);
    fillA_kernel<<<gA, 256, 0, stream>>>(srcs, dsts, gcur, recA, E);
    bucketscan_kernel<<<1, 256, 0, stream>>>(gcur, bbase);
    fillB_kernel<<<FB, 256, 0, stream>>>(gcur, bbase, recA, rowptr, dinv, col, N);

    // ---- layer 1 (K=61) ----
    linscale_kernel<61, float><<<gN, 256, 0, stream>>>(x, W1, dinv, Bh, N);
    gather_kernel<<<4096, 256, 0, stream>>>(rowptr, col, dinv,
                                            (const __half2*)Bh, b1, (__half2*)Ah, N);

    // ---- layer 2 (K=64) ----
    linscale_kernel<64, __half><<<gN, 256, 0, stream>>>(Ah, W2, dinv, Bh, N);
    gather_kernel<<<4096, 256, 0, stream>>>(rowptr, col, dinv,
                                            (const __half2*)Bh, b2, (__half2*)Ah, N);

    // ---- layer 3 (K=64) ----
    linscale_kernel<64, __half><<<gN, 256, 0, stream>>>(Ah, W3, dinv, Bh, N);
    gather_kernel<<<4096, 256, 0, stream>>>(rowptr, col, dinv,
                                            (const __half2*)Bh, b3, (__half2*)Ah, N);

    // ---- MLP head ----
    head_kernel<<<gN, 256, 0, stream>>>(Ah, Wh1, bh1, Wh2, bh2, out, N);
}

// Round 16
// 414.784 us; speedup vs baseline: 1.3314x; 1.0461x over previous
//
#include <hip/hip_runtime.h>
#include <hip/hip_fp16.h>

#define HID 64
#define FSH 8                  // nodes per bucket = 256
#define FB 392                 // buckets: 392*256 = 100352 >= N
#define SCAP 9216              // per-bucket global staging capacity (mean 8163, +11 sigma)
#define FCH 4096               // edges per fillA block (16KB LDS chunk -> high occupancy)
// packed record: loc(8b) << 17 | src(17b); requires N <= 131072

// ---------------- zero int buffer ----------------
__global__ void zero_kernel(int* __restrict__ p, int n) {
    int i = blockIdx.x * blockDim.x + threadIdx.x;
    if (i < n) p[i] = 0;
}

// ---------------- fill phase A: per-block LDS counting sort + coalesced bucket appends ----------------
__global__ __launch_bounds__(256) void fillA_kernel(const int* __restrict__ src,
                                                    const int* __restrict__ dst,
                                                    int* __restrict__ gcur,
                                                    unsigned int* __restrict__ recA,
                                                    int E) {
    __shared__ unsigned int srec[FCH];          // 16 KB
    __shared__ int hist[FB], lbase[FB], lcur[FB], gpos[FB];   // 6.3 KB
    __shared__ int buf[256];
    int t = threadIdx.x;
    int base = blockIdx.x * FCH;
    int lim = E - base;
    if (lim > FCH) lim = FCH;
    if (lim <= 0) return;
    for (int i = t; i < FB; i += 256) hist[i] = 0;
    __syncthreads();
    for (int i = t; i < lim; i += 256) atomicAdd(&hist[dst[base + i] >> FSH], 1);
    __syncthreads();
    // pair-scan hist[0..FB) -> lbase (exclusive)
    int i0 = 2 * t, i1 = 2 * t + 1;
    int a0 = (i0 < FB) ? hist[i0] : 0;
    int a1 = (i1 < FB) ? hist[i1] : 0;
    int pair = a0 + a1;
    buf[t] = pair;
    __syncthreads();
#pragma unroll
    for (int o = 1; o < 256; o <<= 1) {
        int v = (t >= o) ? buf[t - o] : 0;
        __syncthreads();
        buf[t] += v;
        __syncthreads();
    }
    int excl = buf[t] - pair;
    if (i0 < FB) { lbase[i0] = excl;      lcur[i0] = excl; }
    if (i1 < FB) { lbase[i1] = excl + a0; lcur[i1] = excl + a0; }
    __syncthreads();
    // reserve global space (one atomic per bucket per block)
    for (int i = t; i < FB; i += 256) gpos[i] = atomicAdd(&gcur[i], hist[i]);
    __syncthreads();
    // counting-sort records into LDS
    for (int i = t; i < lim; i += 256) {
        int d = dst[base + i];
        int s = src[base + i];
        int bkt = d >> FSH;
        int idx = atomicAdd(&lcur[bkt], 1);
        srec[idx] = ((unsigned int)(d & ((1 << FSH) - 1)) << 17) | (unsigned int)s;
    }
    __syncthreads();
    // coalesced copy of each bucket's run to its global region (16-lane groups, mean run ~10)
    int g16 = t >> 4, lane = t & 15;
    for (int bkt = g16; bkt < FB; bkt += 16) {
        int L = hist[bkt], lb = lbase[bkt], gp = gpos[bkt];
        for (int j = lane; j < L; j += 16) {
            int g = gp + j;
            if (g < SCAP) recA[(size_t)bkt * SCAP + g] = srec[lb + j];
        }
    }
}

// ---------------- exclusive scan of FB bucket totals -> bbase ----------------
__global__ __launch_bounds__(256) void bucketscan_kernel(const int* __restrict__ gcur,
                                                         int* __restrict__ bbase) {
    __shared__ int buf[256];
    int t = threadIdx.x;
    int i0 = 2 * t, i1 = 2 * t + 1;
    int a0 = (i0 < FB) ? min(gcur[i0], SCAP) : 0;
    int a1 = (i1 < FB) ? min(gcur[i1], SCAP) : 0;
    int pair = a0 + a1;
    buf[t] = pair;
    __syncthreads();
#pragma unroll
    for (int o = 1; o < 256; o <<= 1) {
        int v = (t >= o) ? buf[t - o] : 0;
        __syncthreads();
        buf[t] += v;
        __syncthreads();
    }
    int excl = buf[t] - pair;
    if (i0 < FB) bbase[i0] = excl;
    if (i1 < FB) bbase[i1] = excl + a0;
}

// ---------------- fill phase B: per-bucket LDS CSR build + coalesced col writeback ----------------
__global__ __launch_bounds__(256) void fillB_kernel(const int* __restrict__ gcur,
                                                    const int* __restrict__ bbase,
                                                    const unsigned int* __restrict__ recA,
                                                    int* __restrict__ rowptr,
                                                    float* __restrict__ dinv,
                                                    int* __restrict__ col, int N) {
    __shared__ unsigned int lcol[SCAP];         // 36 KB
    __shared__ int hist[256], cur[256], buf[256];
    int b = blockIdx.x, t = threadIdx.x;
    int n0 = b << FSH;
    hist[t] = 0;
    __syncthreads();
    int cnt = gcur[b];
    if (cnt > SCAP) cnt = SCAP;
    const unsigned int* rA = recA + (size_t)b * SCAP;
    for (int r = t; r < cnt; r += 256) atomicAdd(&hist[rA[r] >> 17], 1);
    __syncthreads();
    int a = hist[t];
    buf[t] = a;
    __syncthreads();
#pragma unroll
    for (int o = 1; o < 256; o <<= 1) {
        int v = (t >= o) ? buf[t - o] : 0;
        __syncthreads();
        buf[t] += v;
        __syncthreads();
    }
    int excl = buf[t] - a;           // local exclusive
    int node = n0 + t;
    int rbase = bbase[b];
    if (node <= N) rowptr[node] = rbase + excl;   // includes rowptr[N] at node==N
    if (node < N) dinv[node] = 1.0f / sqrtf((float)(a + 1));
    cur[t] = excl;
    __syncthreads();
    for (int r = t; r < cnt; r += 256) {
        unsigned int rec = rA[r];
        int pos = atomicAdd(&cur[rec >> 17], 1);  // LDS cursor, local position
        lcol[pos] = rec & 0x1ffffu;
    }
    __syncthreads();
    for (int j = t; j < cnt; j += 256) col[rbase + j] = (int)lcol[j];  // coalesced
}

// ---------------- dense linear + dinv scale -> f16 rows: out[n,:] = f16(dinv[n]*(x[n,:]@W)) ----------------
template <int K, typename XT>
__global__ __launch_bounds__(256) void linscale_kernel(const XT* __restrict__ x,
                                                       const float* __restrict__ W,
                                                       const float* __restrict__ dinv,
                                                       __half* __restrict__ out, int N) {
    __shared__ float4 Wl[K * 16];
    const float4* W4 = reinterpret_cast<const float4*>(W);
    for (int i = threadIdx.x; i < K * 16; i += blockDim.x) Wl[i] = W4[i];
    __syncthreads();
    int node = blockIdx.x * blockDim.x + threadIdx.x;
    if (node >= N) return;
    float4 acc[16];
#pragma unroll
    for (int c = 0; c < 16; ++c) acc[c] = make_float4(0.f, 0.f, 0.f, 0.f);
    const XT* xr = x + (size_t)node * K;
    for (int k = 0; k < K; ++k) {
        float xv = (float)xr[k];
#pragma unroll
        for (int c = 0; c < 16; ++c) {
            float4 w = Wl[k * 16 + c];
            acc[c].x += xv * w.x;
            acc[c].y += xv * w.y;
            acc[c].z += xv * w.z;
            acc[c].w += xv * w.w;
        }
    }
    float dv = dinv[node];
    __half2* o = reinterpret_cast<__half2*>(out + (size_t)node * HID);
#pragma unroll
    for (int c = 0; c < 16; ++c) {
        o[c * 2 + 0] = __floats2half2_rn(acc[c].x * dv, acc[c].y * dv);
        o[c * 2 + 1] = __floats2half2_rn(acc[c].z * dv, acc[c].w * dv);
    }
}

// ---------------- gather-aggregate: half2 lanes, 2 rows per wave ----------------
// out[d,:] = f16( relu(dinv[d]*(hs[d,:] + sum_e hs[col[e],:]) + b) )
__global__ __launch_bounds__(256) void gather_kernel(const int* __restrict__ rowptr,
                                                     const int* __restrict__ col,
                                                     const float* __restrict__ dinv,
                                                     const __half2* __restrict__ hs2,
                                                     const float* __restrict__ b,
                                                     __half2* __restrict__ out2, int N) {
    int lane = threadIdx.x & 63;
    int hf = lane >> 5;       // which row of the pair
    int gl = lane & 31;       // lane within 32-group = half2 channel pair
    int wid = (blockIdx.x * blockDim.x + threadIdx.x) >> 6;
    int nw = (gridDim.x * blockDim.x) >> 6;
    float bx = b[2 * gl], by = b[2 * gl + 1];
    for (int dbase = wid * 2; dbase < N; dbase += nw * 2) {
        int d = dbase + hf;
        bool act = d < N;
        int dd = act ? d : N - 1;
        int beg = rowptr[dd];
        int end = act ? rowptr[dd + 1] : beg;
        float2 acc = __half22float2(hs2[((size_t)dd << 5) + gl]);  // self-loop
        for (int ebase = beg; ebase < end; ebase += 32) {
            int e = ebase + gl;
            int cv = (e < end) ? col[e] : 0;   // group-strided load: <=32 edges
            int cnt = end - ebase;
            if (cnt > 32) cnt = 32;
            int k = 0;
            for (; k + 4 <= cnt; k += 4) {
                int s0 = __shfl(cv, k + 0, 32);
                int s1 = __shfl(cv, k + 1, 32);
                int s2 = __shfl(cv, k + 2, 32);
                int s3 = __shfl(cv, k + 3, 32);
                float2 v0 = __half22float2(hs2[((size_t)s0 << 5) + gl]);
                float2 v1 = __half22float2(hs2[((size_t)s1 << 5) + gl]);
                float2 v2 = __half22float2(hs2[((size_t)s2 << 5) + gl]);
                float2 v3 = __half22float2(hs2[((size_t)s3 << 5) + gl]);
                acc.x += (v0.x + v1.x) + (v2.x + v3.x);
                acc.y += (v0.y + v1.y) + (v2.y + v3.y);
            }
            for (; k < cnt; ++k) {
                int s = __shfl(cv, k, 32);
                float2 v = __half22float2(hs2[((size_t)s << 5) + gl]);
                acc.x += v.x; acc.y += v.y;
            }
        }
        if (act) {
            float dv = dinv[d];
            float rx = fmaxf(fmaf(acc.x, dv, bx), 0.f);
            float ry = fmaxf(fmaf(acc.y, dv, by), 0.f);
            out2[((size_t)d << 5) + gl] = __floats2half2_rn(rx, ry);
        }
    }
}

// ---------------- MLP head, thread-per-node: out[i] = relu(h@Wh1+bh1) @ Wh2 + bh2 ----------------
__global__ __launch_bounds__(256) void head_kernel(const __half* __restrict__ h,
                                                   const float* __restrict__ Wh1,
                                                   const float* __restrict__ bh1,
                                                   const float* __restrict__ Wh2,
                                                   const float* __restrict__ bh2,
                                                   float* __restrict__ out, int N) {
    __shared__ float4 Wl[64 * 16];
    __shared__ float bhs[64];
    __shared__ float w2s[64];
    const float4* W4 = reinterpret_cast<const float4*>(Wh1);
    for (int i = threadIdx.x; i < 64 * 16; i += blockDim.x) Wl[i] = W4[i];
    if (threadIdx.x < 64) {
        bhs[threadIdx.x] = bh1[threadIdx.x];
        w2s[threadIdx.x] = Wh2[threadIdx.x];
    }
    __syncthreads();
    int node = blockIdx.x * blockDim.x + threadIdx.x;
    if (node >= N) return;
    float4 acc[16];
#pragma unroll
    for (int c = 0; c < 16; ++c) acc[c] = make_float4(0.f, 0.f, 0.f, 0.f);
    const __half* hr = h + ((size_t)node << 6);
    for (int k = 0; k < 64; ++k) {
        float xv = __half2float(hr[k]);
#pragma unroll
        for (int c = 0; c < 16; ++c) {
            float4 w = Wl[k * 16 + c];
            acc[c].x += xv * w.x;
            acc[c].y += xv * w.y;
            acc[c].z += xv * w.z;
            acc[c].w += xv * w.w;
        }
    }
    float o = 0.f;
#pragma unroll
    for (int c = 0; c < 16; ++c) {
        o += fmaxf(acc[c].x + bhs[4 * c + 0], 0.f) * w2s[4 * c + 0];
        o += fmaxf(acc[c].y + bhs[4 * c + 1], 0.f) * w2s[4 * c + 1];
        o += fmaxf(acc[c].z + bhs[4 * c + 2], 0.f) * w2s[4 * c + 2];
        o += fmaxf(acc[c].w + bhs[4 * c + 3], 0.f) * w2s[4 * c + 3];
    }
    out[node] = o + bh2[0];
}

extern "C" void kernel_launch(void* const* d_in, const int* in_sizes, int n_in,
                              void* d_out, int out_size, void* d_ws, size_t ws_size,
                              hipStream_t stream) {
    const float* x = (const float*)d_in[0];
    const int* edge = (const int*)d_in[1];   // harness passes integer inputs as int32
    const float* W1 = (const float*)d_in[2];
    const float* b1 = (const float*)d_in[3];
    const float* W2 = (const float*)d_in[4];
    const float* b2 = (const float*)d_in[5];
    const float* W3 = (const float*)d_in[6];
    const float* b3 = (const float*)d_in[7];
    const float* Wh1 = (const float*)d_in[8];
    const float* bh1 = (const float*)d_in[9];
    const float* Wh2 = (const float*)d_in[10];
    const float* bh2 = (const float*)d_in[11];

    int N = in_sizes[0] / 61;   // 100000
    int E = in_sizes[1] / 2;    // 3200000
    const int* srcs = edge;
    const int* dsts = edge + E;
    float* out = (float*)d_out;

    // workspace: dinv(N) | rowptr(N+1) | gcur(FB) | bbase(FB) | col(E) | Ah(N*64 f16) | Bh(N*64 f16)
    // fill staging recA (FB*SCAP*4 = 14.45MB) aliases Ah+Bh (25.6MB contiguous, dead until linscale1)
    char* ws = (char*)d_ws;
    size_t off = 0;
    auto alloc = [&](size_t bytes) {
        void* p = ws + off;
        off += (bytes + 255) & ~(size_t)255;
        return p;
    };
    float* dinv = (float*)alloc((size_t)N * 4);
    int* rowptr = (int*)alloc((size_t)(N + 1) * 4);
    int* gcur = (int*)alloc((size_t)FB * 4);
    int* bbase = (int*)alloc((size_t)FB * 4);
    int* col = (int*)alloc((size_t)E * 4);
    __half* Ah = (__half*)alloc((size_t)N * HID * 2);
    __half* Bh = (__half*)alloc((size_t)N * HID * 2);
    if (off > ws_size) return;  // fail cleanly (absmax), not a fault
    unsigned int* recA = (unsigned int*)Ah;  // alias: staging dead after fillB

    int gN = (N + 255) / 256;
    int gA = (E + FCH - 1) / FCH;   // 782

    // ---- CSR build (once, reused by all 3 layers) ----
    zero_kernel<<<(FB + 255) / 256, 256, 0, stream>>>(gcur, FB);
    fillA_kernel<<<gA, 256, 0, stream>>>(srcs, dsts, gcur, recA, E);
    bucketscan_kernel<<<1, 256, 0, stream>>>(gcur, bbase);
    fillB_kernel<<<FB, 256, 0, stream>>>(gcur, bbase, recA, rowptr, dinv, col, N);

    // ---- layer 1 (K=61) ----
    linscale_kernel<61, float><<<gN, 256, 0, stream>>>(x, W1, dinv, Bh, N);
    gather_kernel<<<4096, 256, 0, stream>>>(rowptr, col, dinv,
                                            (const __half2*)Bh, b1, (__half2*)Ah, N);

    // ---- layer 2 (K=64) ----
    linscale_kernel<64, __half><<<gN, 256, 0, stream>>>(Ah, W2, dinv, Bh, N);
    gather_kernel<<<4096, 256, 0, stream>>>(rowptr, col, dinv,
                                            (const __half2*)Bh, b2, (__half2*)Ah, N);

    // ---- layer 3 (K=64) ----
    linscale_kernel<64, __half><<<gN, 256, 0, stream>>>(Ah, W3, dinv, Bh, N);
    gather_kernel<<<4096, 256, 0, stream>>>(rowptr, col, dinv,
                                            (const __half2*)Bh, b3, (__half2*)Ah, N);

    // ---- MLP head ----
    head_kernel<<<gN, 256, 0, stream>>>(Ah, Wh1, bh1, Wh2, bh2, out, N);
}

// Round 18
// 351.726 us; speedup vs baseline: 1.5701x; 1.1793x over previous
//
#include <hip/hip_runtime.h>
#include <hip/hip_fp16.h>

#define HID 64
#define FSH 8                  // nodes per bucket = 256
#define FB 392                 // buckets: 392*256 = 100352 >= N
#define SCAP 9216              // per-bucket global staging capacity (mean 8163, +11 sigma)
#define FCH 4096               // edges per fillA block (16KB LDS chunk -> high occupancy)
// packed record: loc(8b) << 17 | src(17b); requires N <= 131072

__device__ __forceinline__ float2 h2f2(unsigned int bits) {
    __half2 h = __builtin_bit_cast(__half2, bits);
    return __half22float2(h);
}

// ---------------- zero int buffer ----------------
__global__ void zero_kernel(int* __restrict__ p, int n) {
    int i = blockIdx.x * blockDim.x + threadIdx.x;
    if (i < n) p[i] = 0;
}

// ---------------- fill phase A: per-block LDS counting sort + coalesced bucket appends ----------------
__global__ __launch_bounds__(256) void fillA_kernel(const int* __restrict__ src,
                                                    const int* __restrict__ dst,
                                                    int* __restrict__ gcur,
                                                    unsigned int* __restrict__ recA,
                                                    int E) {
    __shared__ unsigned int srec[FCH];          // 16 KB
    __shared__ int hist[FB], lbase[FB], lcur[FB], gpos[FB];   // 6.3 KB
    __shared__ int buf[256];
    int t = threadIdx.x;
    int base = blockIdx.x * FCH;
    int lim = E - base;
    if (lim > FCH) lim = FCH;
    if (lim <= 0) return;
    for (int i = t; i < FB; i += 256) hist[i] = 0;
    __syncthreads();
    for (int i = t; i < lim; i += 256) atomicAdd(&hist[dst[base + i] >> FSH], 1);
    __syncthreads();
    // pair-scan hist[0..FB) -> lbase (exclusive)
    int i0 = 2 * t, i1 = 2 * t + 1;
    int a0 = (i0 < FB) ? hist[i0] : 0;
    int a1 = (i1 < FB) ? hist[i1] : 0;
    int pair = a0 + a1;
    buf[t] = pair;
    __syncthreads();
#pragma unroll
    for (int o = 1; o < 256; o <<= 1) {
        int v = (t >= o) ? buf[t - o] : 0;
        __syncthreads();
        buf[t] += v;
        __syncthreads();
    }
    int excl = buf[t] - pair;
    if (i0 < FB) { lbase[i0] = excl;      lcur[i0] = excl; }
    if (i1 < FB) { lbase[i1] = excl + a0; lcur[i1] = excl + a0; }
    __syncthreads();
    // reserve global space (one atomic per bucket per block)
    for (int i = t; i < FB; i += 256) gpos[i] = atomicAdd(&gcur[i], hist[i]);
    __syncthreads();
    // counting-sort records into LDS
    for (int i = t; i < lim; i += 256) {
        int d = dst[base + i];
        int s = src[base + i];
        int bkt = d >> FSH;
        int idx = atomicAdd(&lcur[bkt], 1);
        srec[idx] = ((unsigned int)(d & ((1 << FSH) - 1)) << 17) | (unsigned int)s;
    }
    __syncthreads();
    // coalesced copy of each bucket's run to its global region (16-lane groups, mean run ~10)
    int g16 = t >> 4, lane = t & 15;
    for (int bkt = g16; bkt < FB; bkt += 16) {
        int L = hist[bkt], lb = lbase[bkt], gp = gpos[bkt];
        for (int j = lane; j < L; j += 16) {
            int g = gp + j;
            if (g < SCAP) recA[(size_t)bkt * SCAP + g] = srec[lb + j];
        }
    }
}

// ---------------- fill phase B: inline bucket-prefix + per-bucket LDS CSR + coalesced col ----------------
__global__ __launch_bounds__(256) void fillB_kernel(const int* __restrict__ gcur,
                                                    const unsigned int* __restrict__ recA,
                                                    int* __restrict__ rowptr,
                                                    float* __restrict__ dinv,
                                                    int* __restrict__ col, int N) {
    __shared__ unsigned int lcol[SCAP];         // 36 KB
    __shared__ int hist[256], cur[256], buf[256];
    int b = blockIdx.x, t = threadIdx.x;
    int n0 = b << FSH;
    // rbase = sum_{i<b} min(gcur[i],SCAP)
    int p = 0;
    for (int i = t; i < b; i += 256) p += min(gcur[i], SCAP);
    buf[t] = p;
    __syncthreads();
#pragma unroll
    for (int o = 128; o > 0; o >>= 1) {
        if (t < o) buf[t] += buf[t + o];
        __syncthreads();
    }
    int rbase = buf[0];
    __syncthreads();
    hist[t] = 0;
    __syncthreads();
    int cnt = gcur[b];
    if (cnt > SCAP) cnt = SCAP;
    const unsigned int* rA = recA + (size_t)b * SCAP;
    for (int r = t; r < cnt; r += 256) atomicAdd(&hist[rA[r] >> 17], 1);
    __syncthreads();
    int a = hist[t];
    buf[t] = a;
    __syncthreads();
#pragma unroll
    for (int o = 1; o < 256; o <<= 1) {
        int v = (t >= o) ? buf[t - o] : 0;
        __syncthreads();
        buf[t] += v;
        __syncthreads();
    }
    int excl = buf[t] - a;           // local exclusive
    int node = n0 + t;
    if (node <= N) rowptr[node] = rbase + excl;   // includes rowptr[N] at node==N
    if (node < N) dinv[node] = 1.0f / sqrtf((float)(a + 1));
    cur[t] = excl;
    __syncthreads();
    for (int r = t; r < cnt; r += 256) {
        unsigned int rec = rA[r];
        int pos = atomicAdd(&cur[rec >> 17], 1);  // LDS cursor, local position
        lcol[pos] = rec & 0x1ffffu;
    }
    __syncthreads();
    for (int j = t; j < cnt; j += 256) col[rbase + j] = (int)lcol[j];  // coalesced
}

// ---------------- dense linear (f32 input, K=61) + dinv scale -> f16 rows ----------------
__global__ __launch_bounds__(256) void linscale61_kernel(const float* __restrict__ x,
                                                         const float* __restrict__ W,
                                                         const float* __restrict__ dinv,
                                                         __half* __restrict__ out, int N) {
    __shared__ float4 Wl[61 * 16];
    const float4* W4 = reinterpret_cast<const float4*>(W);
    for (int i = threadIdx.x; i < 61 * 16; i += blockDim.x) Wl[i] = W4[i];
    __syncthreads();
    int node = blockIdx.x * blockDim.x + threadIdx.x;
    if (node >= N) return;
    float4 acc[16];
#pragma unroll
    for (int c = 0; c < 16; ++c) acc[c] = make_float4(0.f, 0.f, 0.f, 0.f);
    const float* xr = x + (size_t)node * 61;
    for (int k = 0; k < 61; ++k) {
        float xv = xr[k];
#pragma unroll
        for (int c = 0; c < 16; ++c) {
            float4 w = Wl[k * 16 + c];
            acc[c].x += xv * w.x;
            acc[c].y += xv * w.y;
            acc[c].z += xv * w.z;
            acc[c].w += xv * w.w;
        }
    }
    float dv = dinv[node];
    __half2* o = reinterpret_cast<__half2*>(out + (size_t)node * HID);
#pragma unroll
    for (int c = 0; c < 16; ++c) {
        o[c * 2 + 0] = __floats2half2_rn(acc[c].x * dv, acc[c].y * dv);
        o[c * 2 + 1] = __floats2half2_rn(acc[c].z * dv, acc[c].w * dv);
    }
}

// ---------------- dense linear (f16 input, K=64, uint4-vectorized) + dinv scale -> f16 ----------------
__global__ __launch_bounds__(256) void linscale64h_kernel(const __half* __restrict__ x,
                                                          const float* __restrict__ W,
                                                          const float* __restrict__ dinv,
                                                          __half* __restrict__ out, int N) {
    __shared__ float4 Wl[64 * 16];
    const float4* W4 = reinterpret_cast<const float4*>(W);
    for (int i = threadIdx.x; i < 64 * 16; i += blockDim.x) Wl[i] = W4[i];
    __syncthreads();
    int node = blockIdx.x * blockDim.x + threadIdx.x;
    if (node >= N) return;
    float4 acc[16];
#pragma unroll
    for (int c = 0; c < 16; ++c) acc[c] = make_float4(0.f, 0.f, 0.f, 0.f);
    const uint4* xr4 = reinterpret_cast<const uint4*>(x + ((size_t)node << 6));
#pragma unroll
    for (int c8 = 0; c8 < 8; ++c8) {
        uint4 pk = xr4[c8];
        float2 f0 = h2f2(pk.x), f1 = h2f2(pk.y), f2 = h2f2(pk.z), f3 = h2f2(pk.w);
        float xv[8] = {f0.x, f0.y, f1.x, f1.y, f2.x, f2.y, f3.x, f3.y};
#pragma unroll
        for (int j = 0; j < 8; ++j) {
            int k = c8 * 8 + j;
#pragma unroll
            for (int c = 0; c < 16; ++c) {
                float4 w = Wl[k * 16 + c];
                acc[c].x += xv[j] * w.x;
                acc[c].y += xv[j] * w.y;
                acc[c].z += xv[j] * w.z;
                acc[c].w += xv[j] * w.w;
            }
        }
    }
    float dv = dinv[node];
    __half2* o = reinterpret_cast<__half2*>(out + ((size_t)node << 6));
#pragma unroll
    for (int c = 0; c < 16; ++c) {
        o[c * 2 + 0] = __floats2half2_rn(acc[c].x * dv, acc[c].y * dv);
        o[c * 2 + 1] = __floats2half2_rn(acc[c].z * dv, acc[c].w * dv);
    }
}

// ---------------- gather-aggregate: half2 lanes, 2 rows/wave, 16-deep load pipeline ----------------
// out[d,:] = f16( relu(dinv[d]*(hs[d,:] + sum_e hs[col[e],:]) + b) )
__global__ __launch_bounds__(256) void gather_kernel(const int* __restrict__ rowptr,
                                                     const int* __restrict__ col,
                                                     const float* __restrict__ dinv,
                                                     const __half2* __restrict__ hs2,
                                                     const float* __restrict__ b,
                                                     __half2* __restrict__ out2, int N) {
    int lane = threadIdx.x & 63;
    int hf = lane >> 5;       // which row of the pair
    int gl = lane & 31;       // lane within 32-group = half2 channel pair
    int wid = (blockIdx.x * blockDim.x + threadIdx.x) >> 6;
    int nw = (gridDim.x * blockDim.x) >> 6;
    float bx = b[2 * gl], by = b[2 * gl + 1];
    for (int dbase = wid * 2; dbase < N; dbase += nw * 2) {
        int d = dbase + hf;
        bool act = d < N;
        int dd = act ? d : N - 1;
        int beg = rowptr[dd];
        int end = act ? rowptr[dd + 1] : beg;
        float2 acc0 = __half22float2(hs2[((size_t)dd << 5) + gl]);  // self-loop
        float2 acc1 = make_float2(0.f, 0.f);
        for (int ebase = beg; ebase < end; ebase += 32) {
            int e = ebase + gl;
            int cv = (e < end) ? col[e] : 0;   // OOB lanes -> row 0 (valid, L1-hot)
            int cnt = end - ebase;
            {   // chunk 0: k = 0..15 — 16 loads issued back-to-back
                unsigned int r[16];
#pragma unroll
                for (int k = 0; k < 16; ++k) {
                    int s = __shfl(cv, k, 32);
                    r[k] = *reinterpret_cast<const unsigned int*>(hs2 + ((size_t)s << 5) + gl);
                }
#pragma unroll
                for (int k = 0; k < 16; ++k) {
                    unsigned int bits = (k < cnt) ? r[k] : 0u;
                    float2 v = h2f2(bits);
                    if (k & 1) { acc1.x += v.x; acc1.y += v.y; }
                    else       { acc0.x += v.x; acc0.y += v.y; }
                }
            }
            if (cnt > 16) {   // chunk 1: k = 16..31
                unsigned int r[16];
#pragma unroll
                for (int k = 0; k < 16; ++k) {
                    int s = __shfl(cv, k + 16, 32);
                    r[k] = *reinterpret_cast<const unsigned int*>(hs2 + ((size_t)s << 5) + gl);
                }
#pragma unroll
                for (int k = 0; k < 16; ++k) {
                    unsigned int bits = (k + 16 < cnt) ? r[k] : 0u;
                    float2 v = h2f2(bits);
                    if (k & 1) { acc1.x += v.x; acc1.y += v.y; }
                    else       { acc0.x += v.x; acc0.y += v.y; }
                }
            }
        }
        if (act) {
            float dv = dinv[d];
            float rx = fmaxf(fmaf(acc0.x + acc1.x, dv, bx), 0.f);
            float ry = fmaxf(fmaf(acc0.y + acc1.y, dv, by), 0.f);
            out2[((size_t)d << 5) + gl] = __floats2half2_rn(rx, ry);
        }
    }
}

// ---------------- MLP head, thread-per-node, uint4-vectorized h reads ----------------
__global__ __launch_bounds__(256) void head_kernel(const __half* __restrict__ h,
                                                   const float* __restrict__ Wh1,
                                                   const float* __restrict__ bh1,
                                                   const float* __restrict__ Wh2,
                                                   const float* __restrict__ bh2,
                                                   float* __restrict__ out, int N) {
    __shared__ float4 Wl[64 * 16];
    __shared__ float bhs[64];
    __shared__ float w2s[64];
    const float4* W4 = reinterpret_cast<const float4*>(Wh1);
    for (int i = threadIdx.x; i < 64 * 16; i += blockDim.x) Wl[i] = W4[i];
    if (threadIdx.x < 64) {
        bhs[threadIdx.x] = bh1[threadIdx.x];
        w2s[threadIdx.x] = Wh2[threadIdx.x];
    }
    __syncthreads();
    int node = blockIdx.x * blockDim.x + threadIdx.x;
    if (node >= N) return;
    float4 acc[16];
#pragma unroll
    for (int c = 0; c < 16; ++c) acc[c] = make_float4(0.f, 0.f, 0.f, 0.f);
    const uint4* hr4 = reinterpret_cast<const uint4*>(h + ((size_t)node << 6));
#pragma unroll
    for (int c8 = 0; c8 < 8; ++c8) {
        uint4 pk = hr4[c8];
        float2 f0 = h2f2(pk.x), f1 = h2f2(pk.y), f2 = h2f2(pk.z), f3 = h2f2(pk.w);
        float xv[8] = {f0.x, f0.y, f1.x, f1.y, f2.x, f2.y, f3.x, f3.y};
#pragma unroll
        for (int j = 0; j < 8; ++j) {
            int k = c8 * 8 + j;
#pragma unroll
            for (int c = 0; c < 16; ++c) {
                float4 w = Wl[k * 16 + c];
                acc[c].x += xv[j] * w.x;
                acc[c].y += xv[j] * w.y;
                acc[c].z += xv[j] * w.z;
                acc[c].w += xv[j] * w.w;
            }
        }
    }
    float o = 0.f;
#pragma unroll
    for (int c = 0; c < 16; ++c) {
        o += fmaxf(acc[c].x + bhs[4 * c + 0], 0.f) * w2s[4 * c + 0];
        o += fmaxf(acc[c].y + bhs[4 * c + 1], 0.f) * w2s[4 * c + 1];
        o += fmaxf(acc[c].z + bhs[4 * c + 2], 0.f) * w2s[4 * c + 2];
        o += fmaxf(acc[c].w + bhs[4 * c + 3], 0.f) * w2s[4 * c + 3];
    }
    out[node] = o + bh2[0];
}

extern "C" void kernel_launch(void* const* d_in, const int* in_sizes, int n_in,
                              void* d_out, int out_size, void* d_ws, size_t ws_size,
                              hipStream_t stream) {
    const float* x = (const float*)d_in[0];
    const int* edge = (const int*)d_in[1];   // harness passes integer inputs as int32
    const float* W1 = (const float*)d_in[2];
    const float* b1 = (const float*)d_in[3];
    const float* W2 = (const float*)d_in[4];
    const float* b2 = (const float*)d_in[5];
    const float* W3 = (const float*)d_in[6];
    const float* b3 = (const float*)d_in[7];
    const float* Wh1 = (const float*)d_in[8];
    const float* bh1 = (const float*)d_in[9];
    const float* Wh2 = (const float*)d_in[10];
    const float* bh2 = (const float*)d_in[11];

    int N = in_sizes[0] / 61;   // 100000
    int E = in_sizes[1] / 2;    // 3200000
    const int* srcs = edge;
    const int* dsts = edge + E;
    float* out = (float*)d_out;

    // workspace: dinv(N) | rowptr(N+1) | gcur(FB) | col(E) | Ah(N*64 f16) | Bh(N*64 f16)
    // fill staging recA (FB*SCAP*4 = 14.45MB) aliases Ah+Bh (25.6MB contiguous, dead until linscale1)
    char* ws = (char*)d_ws;
    size_t off = 0;
    auto alloc = [&](size_t bytes) {
        void* p = ws + off;
        off += (bytes + 255) & ~(size_t)255;
        return p;
    };
    float* dinv = (float*)alloc((size_t)N * 4);
    int* rowptr = (int*)alloc((size_t)(N + 1) * 4);
    int* gcur = (int*)alloc((size_t)FB * 4);
    int* col = (int*)alloc((size_t)E * 4);
    __half* Ah = (__half*)alloc((size_t)N * HID * 2);
    __half* Bh = (__half*)alloc((size_t)N * HID * 2);
    if (off > ws_size) return;  // fail cleanly (absmax), not a fault
    unsigned int* recA = (unsigned int*)Ah;  // alias: staging dead after fillB

    int gN = (N + 255) / 256;
    int gA = (E + FCH - 1) / FCH;   // 782

    // ---- CSR build (once, reused by all 3 layers) ----
    zero_kernel<<<(FB + 255) / 256, 256, 0, stream>>>(gcur, FB);
    fillA_kernel<<<gA, 256, 0, stream>>>(srcs, dsts, gcur, recA, E);
    fillB_kernel<<<FB, 256, 0, stream>>>(gcur, recA, rowptr, dinv, col, N);

    // ---- layer 1 (K=61) ----
    linscale61_kernel<<<gN, 256, 0, stream>>>(x, W1, dinv, Bh, N);
    gather_kernel<<<4096, 256, 0, stream>>>(rowptr, col, dinv,
                                            (const __half2*)Bh, b1, (__half2*)Ah, N);

    // ---- layer 2 (K=64) ----
    linscale64h_kernel<<<gN, 256, 0, stream>>>(Ah, W2, dinv, Bh, N);
    gather_kernel<<<4096, 256, 0, stream>>>(rowptr, col, dinv,
                                            (const __half2*)Bh, b2, (__half2*)Ah, N);

    // ---- layer 3 (K=64) ----
    linscale64h_kernel<<<gN, 256, 0, stream>>>(Ah, W3, dinv, Bh, N);
    gather_kernel<<<4096, 256, 0, stream>>>(rowptr, col, dinv,
                                            (const __half2*)Bh, b3, (__half2*)Ah, N);

    // ---- MLP head ----
    head_kernel<<<gN, 256, 0, stream>>>(Ah, Wh1, bh1, Wh2, bh2, out, N);
}